// Round 8
// baseline (1644.770 us; speedup 1.0000x reference)
//
#include <hip/hip_runtime.h>
#include <hip/hip_bf16.h>
#include <stdint.h>

typedef __bf16 bf16_t;
typedef __bf16 bf16x8 __attribute__((ext_vector_type(8)));
typedef __bf16 bf16x4 __attribute__((ext_vector_type(4)));
typedef float  floatx4 __attribute__((ext_vector_type(4)));

#define T_STEPS 128
#define BATCH   64
#define EDIM    1024
#define HDIM    1024
#define VOCAB   10000
#define MROWS   (T_STEPS * BATCH)   // 8192
#define RNN_BLOCKS 128              // 64 layer-0 + 64 layer-1
#define DEC_BLOCKS 128              // fused X0+decode consumer blocks
#define BH      (BATCH * HDIM)
#define FSTRIDE 16                  // RNN flags padded to one 64B line each
#define XF_OFF  (128 * FSTRIDE)     // X0-unit flags start here in flags buffer
#define OUT0    ((size_t)MROWS * VOCAB)

__device__ __forceinline__ floatx4 mfma16(bf16x8 a, bf16x8 b, floatx4 c) {
    return __builtin_amdgcn_mfma_f32_16x16x32_bf16(a, b, c, 0, 0, 0);
}

// async global->LDS, 16B per lane. LDS dest must be wave-uniform base + lane*16.
__device__ __forceinline__ void gl_lds16(const bf16_t* g, bf16_t* l) {
    __builtin_amdgcn_global_load_lds(
        (const __attribute__((address_space(1))) void*)g,
        (__attribute__((address_space(3))) void*)l, 16, 0, 0);
}

// Coherence-point store: bypasses L1/L2 (sc0 sc1), lands at L3 so other XCDs'
// first-touch plain loads see it WITHOUT any buffer_wbl2/buffer_inv.
__device__ __forceinline__ void store_bf16_bypass(bf16_t* p, float v) {
    union { bf16_t b; unsigned short u; } cv;
    cv.b = (bf16_t)v;
    unsigned int d = cv.u;
    asm volatile("global_store_short %0, %1, off sc0 sc1"
                 :: "v"(p), "v"(d) : "memory");
}

__device__ __forceinline__ void wait_flag1(const int* p) {
    while (__hip_atomic_load(p, __ATOMIC_RELAXED, __HIP_MEMORY_SCOPE_AGENT) == 0)
        __builtin_amdgcn_s_sleep(1);
}

// ---------------- single setup kernel: all f2b + gather + init ----------------
// blocks [0,4096): f2b of Win0/Wh0/Win1/Wh1 (1024 blocks each)
// [4096,14096): f2b Wdec; [14096,22288): gather; [22288,22352): init state+flags

__global__ void setup_kernel(const float* __restrict__ emb,
                             const float* __restrict__ W_in0, const float* __restrict__ Wh0,
                             const float* __restrict__ W_in1, const float* __restrict__ Wh1,
                             const float* __restrict__ Wdec,
                             const float* __restrict__ hidden, const int* __restrict__ tok,
                             bf16_t* __restrict__ Xemb,
                             bf16_t* __restrict__ Win0b, bf16_t* __restrict__ Wh0b,
                             bf16_t* __restrict__ Win1b, bf16_t* __restrict__ Wh1b,
                             bf16_t* __restrict__ Wdecb,
                             bf16_t* __restrict__ h0all, bf16_t* __restrict__ h1all,
                             int* __restrict__ flags) {
    const int b = blockIdx.x, tid = threadIdx.x;
    if (b < 4096) {
        const int which = b >> 10;
        const float* s = which == 0 ? W_in0 : which == 1 ? Wh0 : which == 2 ? W_in1 : Wh1;
        bf16_t*      d = which == 0 ? Win0b : which == 1 ? Wh0b : which == 2 ? Win1b : Wh1b;
        int i = ((b & 1023) * 256 + tid) * 4;
        float4 v = *(const float4*)(s + i);
        bf16x4 o; o.x = (bf16_t)v.x; o.y = (bf16_t)v.y; o.z = (bf16_t)v.z; o.w = (bf16_t)v.w;
        *(bf16x4*)(d + i) = o;
    } else if (b < 14096) {
        int i = ((b - 4096) * 256 + tid) * 4;
        float4 v = *(const float4*)(Wdec + i);
        bf16x4 o; o.x = (bf16_t)v.x; o.y = (bf16_t)v.y; o.z = (bf16_t)v.z; o.w = (bf16_t)v.w;
        *(bf16x4*)(Wdecb + i) = o;
    } else if (b < 22288) {
        int row = b - 14096;
        int t = tok[row];
        int e = tid * 4;
        float4 v = *(const float4*)(emb + (size_t)t * EDIM + e);
        bf16x4 o; o.x = (bf16_t)v.x; o.y = (bf16_t)v.y; o.z = (bf16_t)v.z; o.w = (bf16_t)v.w;
        *(bf16x4*)(Xemb + (size_t)row * EDIM + e) = o;
    } else {
        int i = ((b - 22288) * 256 + tid) * 4;   // 0..65532
        float4 v0 = *(const float4*)(hidden + i);
        float4 v1 = *(const float4*)(hidden + BH + i);
        bf16x4 o0, o1;
        o0.x = (bf16_t)v0.x; o0.y = (bf16_t)v0.y; o0.z = (bf16_t)v0.z; o0.w = (bf16_t)v0.w;
        o1.x = (bf16_t)v1.x; o1.y = (bf16_t)v1.y; o1.z = (bf16_t)v1.z; o1.w = (bf16_t)v1.w;
        *(bf16x4*)(h0all + i) = o0;   // h0[-1] -> slot 0
        *(bf16x4*)(h1all + i) = o1;   // h1[-1] -> slot 0
        if (b == 22288)
            for (int j = tid; j < XF_OFF + 512; j += 256) flags[j] = 0;
    }
}

// ---------------- fused X0-GEMM + RNN + streaming decode ----------------
// 256 blocks, all co-resident (256 CUs):
//   0..63   layer-0 (Wh0 slice in LDS)   -- round-4 RNN structure
//   64..127 layer-1 (Win1+Wh1 in LDS)
//   128..255 helper blocks:
//     phase A: X0 = Xemb @ Win0^T + b0 as 512 (mtile,ntile) units in t-major
//              order; publish per-unit xf flags. L0 gates its X0[t] prefetch on
//              xf[(t/2)*8 + (cb>>3)] (one flag: its 16 cols lie in one n-tile).
//              L0 has slack vs the L1 pacer, so the check is off-path.
//     phase B: logits[t] = h1[t] @ Wdec^T + bdec. FIXED-vt mapping: block owns
//              one vocab tile (vt<49: tp range split across 2 blocks) so its
//              256KB Wdec tile stays L2-resident across t-pairs (round-7's
//              any-unit order re-pulled Wdec from HBM: 888MB FETCH_SIZE).
//              Exactly 79 active blocks per t-pair, 1 unit each (~15us < 17us
//              RNN supply period). Consumes f1 flags; pure consumer.
// Finalize folded in: L0/L1 write their fp32 final states at t=127.

__global__ __launch_bounds__(256, 1) void fused_kernel(
    bf16_t* __restrict__ X0,           // [8192][1024] workspace
    const bf16_t* __restrict__ Xemb,
    const bf16_t* __restrict__ Win0b,
    const float*  __restrict__ b0,
    const bf16_t* __restrict__ Wh0b,
    const bf16_t* __restrict__ Win1b,
    const bf16_t* __restrict__ Wh1b,
    const float*  __restrict__ b1,
    const bf16_t* __restrict__ Wdecb,  // [10000][1024]
    const float*  __restrict__ bdec,
    float* __restrict__ out,           // logits [8192][10000] fp32 + final states
    bf16_t* __restrict__ h0all,        // [129][64][1024], slot s = h0[s-1]
    bf16_t* __restrict__ h1all,        // [129][64][1024], slot s = h1[s-1]
    int* __restrict__ flags)           // f0[64*FS], f1[64*FS], xf[512]
{
    __shared__ __align__(16) char smem[65536];
    const int tid  = threadIdx.x;
    const int lane = tid & 63;
    const int wave = tid >> 6;
    const int quad = lane >> 4;
    const int l16  = lane & 15;
    int* f0 = flags;
    int* f1 = flags + 64 * FSTRIDE;
    int* xf = flags + XF_OFF;
    const floatx4 fzero = {0.f, 0.f, 0.f, 0.f};

    if (blockIdx.x >= RNN_BLOCKS) {
        // ================= helper blocks =================
        const int d  = blockIdx.x - RNN_BLOCKS;
        const int wm = wave & 1;
        const int wn = wave >> 1;
        bf16_t* sA = (bf16_t*)smem;            // 8 KB
        bf16_t* sW = (bf16_t*)(smem + 8192);   // 8 KB

        // ---- phase A: X0 GEMM, t-major units (u -> mtile=u/8, nt=u%8) ----
        for (int u = d; u < 512; u += DEC_BLOCKS) {
            const int mTile = (u >> 3) * 128;
            const int nTile = (u & 7) * 128;
            floatx4 acc[4][4];
            #pragma unroll
            for (int i = 0; i < 4; ++i)
                #pragma unroll
                for (int j = 0; j < 4; ++j) acc[i][j] = fzero;
            for (int kk = 0; kk < EDIM; kk += 32) {
                __syncthreads();
                #pragma unroll
                for (int j = 0; j < 2; ++j) {
                    int c   = tid + j * 256;
                    int row = c >> 2;
                    int sub = c & 3;
                    gl_lds16(Xemb  + (size_t)(mTile + row) * EDIM + kk + sub * 8, sA + c * 8);
                    gl_lds16(Win0b + (size_t)(nTile + row) * EDIM + kk + sub * 8, sW + c * 8);
                }
                __syncthreads();
                bf16x8 af[4], wf[4];
                #pragma unroll
                for (int mi = 0; mi < 4; ++mi)
                    af[mi] = *(const bf16x8*)(sA + (wm * 64 + mi * 16 + l16) * 32 + quad * 8);
                #pragma unroll
                for (int ni = 0; ni < 4; ++ni)
                    wf[ni] = *(const bf16x8*)(sW + (wn * 64 + ni * 16 + l16) * 32 + quad * 8);
                #pragma unroll
                for (int mi = 0; mi < 4; ++mi)
                    #pragma unroll
                    for (int ni = 0; ni < 4; ++ni)
                        acc[mi][ni] = mfma16(af[mi], wf[ni], acc[mi][ni]);
            }
            #pragma unroll
            for (int ni = 0; ni < 4; ++ni) {
                int col = nTile + wn * 64 + ni * 16 + l16;
                float bv = b0[col];
                #pragma unroll
                for (int mi = 0; mi < 4; ++mi) {
                    #pragma unroll
                    for (int r = 0; r < 4; ++r) {
                        int row = mTile + wm * 64 + mi * 16 + quad * 4 + r;
                        store_bf16_bypass(X0 + (size_t)row * HDIM + col,
                                          acc[mi][ni][r] + bv);
                    }
                }
            }
            asm volatile("s_waitcnt vmcnt(0)" ::: "memory");
            __syncthreads();
            if (tid == 0)
                __hip_atomic_store(&xf[u], 1, __ATOMIC_RELAXED, __HIP_MEMORY_SCOPE_AGENT);
            __syncthreads();
        }

        // ---- phase B: logits, fixed-vt ----
        int vt, tp0, tpN;
        if (d < 79) { vt = d;      tp0 = 0;  tpN = (d < 49) ? 32 : 64; }
        else        { vt = d - 79; tp0 = 32; tpN = 64; }
        const bf16_t* Adec = h1all + BH;       // row r = h1[r/64][r%64]
        const int nTile = vt * 128;
        int vc = 0;
        for (int tp = tp0; tp < tpN; ++tp) {
            const int need = 2 * tp + 2;
            if (wave == 0) {
                while (!__all(vc >= need)) {
                    if (vc < need) {
                        vc = __hip_atomic_load(&f1[lane * FSTRIDE], __ATOMIC_RELAXED,
                                               __HIP_MEMORY_SCOPE_AGENT);
                        if (vc < need) __builtin_amdgcn_s_sleep(32);
                    }
                }
            }
            __syncthreads();
            const int mTile = tp * 128;
            floatx4 acc[4][4];
            #pragma unroll
            for (int i = 0; i < 4; ++i)
                #pragma unroll
                for (int j = 0; j < 4; ++j) acc[i][j] = fzero;
            for (int kk = 0; kk < HDIM; kk += 32) {
                __syncthreads();
                #pragma unroll
                for (int j = 0; j < 2; ++j) {
                    int c   = tid + j * 256;
                    int row = c >> 2;
                    int sub = c & 3;
                    gl_lds16(Adec + (size_t)(mTile + row) * HDIM + kk + sub * 8, sA + c * 8);
                    int wrow = nTile + row;
                    if (wrow >= VOCAB) wrow = VOCAB - 1;
                    gl_lds16(Wdecb + (size_t)wrow * HDIM + kk + sub * 8, sW + c * 8);
                }
                __syncthreads();
                bf16x8 af[4], wf[4];
                #pragma unroll
                for (int mi = 0; mi < 4; ++mi)
                    af[mi] = *(const bf16x8*)(sA + (wm * 64 + mi * 16 + l16) * 32 + quad * 8);
                #pragma unroll
                for (int ni = 0; ni < 4; ++ni)
                    wf[ni] = *(const bf16x8*)(sW + (wn * 64 + ni * 16 + l16) * 32 + quad * 8);
                #pragma unroll
                for (int mi = 0; mi < 4; ++mi)
                    #pragma unroll
                    for (int ni = 0; ni < 4; ++ni)
                        acc[mi][ni] = mfma16(af[mi], wf[ni], acc[mi][ni]);
            }
            #pragma unroll
            for (int ni = 0; ni < 4; ++ni) {
                int col = nTile + wn * 64 + ni * 16 + l16;
                if (col < VOCAB) {
                    float bv = bdec[col];
                    #pragma unroll
                    for (int mi = 0; mi < 4; ++mi) {
                        #pragma unroll
                        for (int r = 0; r < 4; ++r) {
                            int row = mTile + wm * 64 + mi * 16 + quad * 4 + r;
                            out[(size_t)row * VOCAB + col] = acc[mi][ni][r] + bv;
                        }
                    }
                }
            }
            __syncthreads();   // LDS reuse guard
        }
        return;
    }

    // ================= RNN blocks (round-4 structure) =================
    const bool isL1 = blockIdx.x >= 64;
    const int cb    = blockIdx.x & 63;
    const int cbase = cb * 16;
    const int colg  = cbase + l16;
    const int arow  = (wave * 16 + l16) * HDIM;
    const int orow0 = wave * 16 + quad * 4;

    // ---- stage weight slices into LDS (once) ----
    {
        const bf16_t* W0 = isL1 ? Win1b : Wh0b;
        for (int c = tid; c < 2048; c += 256) {
            int kc2 = c >> 6, ln = c & 63;
            const bf16_t* src = W0 + (size_t)(cbase + (ln & 15)) * HDIM + kc2 * 32 + (ln >> 4) * 8;
            *(int4*)(smem + c * 16) = *(const int4*)src;
        }
        if (isL1) {
            for (int c = tid; c < 2048; c += 256) {
                int kc2 = c >> 6, ln = c & 63;
                const bf16_t* src = Wh1b + (size_t)(cbase + (ln & 15)) * HDIM + kc2 * 32 + (ln >> 4) * 8;
                *(int4*)(smem + 32768 + c * 16) = *(const int4*)src;
            }
        }
    }
    __syncthreads();

    if (!isL1) {
        // ---------------- layer 0 ----------------
        const int nt0 = cb >> 3;                 // this block's X0 n-tile
        wait_flag1(&xf[nt0]);                    // mtile 0, our n-tile
        float xr[4];
        #pragma unroll
        for (int r = 0; r < 4; ++r)
            xr[r] = (float)X0[(size_t)(orow0 + r) * HDIM + colg];
        int xdone = 0;
        int vc = 0;   // per-lane monotone cache of f0[lane] (wave0 only)
        for (int t = 0; t < T_STEPS; ++t) {
            if (t > 0) {
                if (wave == 0) {
                    while (!__all(vc >= t)) {
                        if (vc < t) {
                            vc = __hip_atomic_load(&f0[lane * FSTRIDE], __ATOMIC_RELAXED,
                                                   __HIP_MEMORY_SCOPE_AGENT);
                            if (vc < t) __builtin_amdgcn_s_sleep(1);
                        }
                    }
                }
                __syncthreads();
            }
            const bf16_t* Ap = h0all + (size_t)t * BH;
            bf16x8 av[32];
            #pragma unroll
            for (int kc = 0; kc < 32; ++kc)
                av[kc] = *(const bf16x8*)(Ap + arow + kc * 32 + quad * 8);
            float xn[4];
            if (t + 1 < T_STEPS) {
                int m = (t + 1) >> 1;
                if (m > xdone) { wait_flag1(&xf[m * 8 + nt0]); xdone = m; }
                #pragma unroll
                for (int r = 0; r < 4; ++r)
                    xn[r] = (float)X0[((size_t)(t + 1) * BATCH + orow0 + r) * HDIM + colg];
            }
            __builtin_amdgcn_sched_barrier(0);
            floatx4 a0 = fzero, a1 = fzero;
            #pragma unroll
            for (int kc = 0; kc < 32; ++kc) {
                bf16x8 wv = *(const bf16x8*)(smem + kc * 1024 + lane * 16);
                if (kc & 1) a1 = mfma16(av[kc], wv, a1);
                else        a0 = mfma16(av[kc], wv, a0);
            }
            bf16_t* dst = h0all + (size_t)(t + 1) * BH;
            #pragma unroll
            for (int r = 0; r < 4; ++r) {
                float hv = tanhf(xr[r] + a0[r] + a1[r]);
                store_bf16_bypass(dst + (size_t)(orow0 + r) * HDIM + colg, hv);
                if (t == T_STEPS - 1)
                    out[OUT0 + (size_t)(orow0 + r) * HDIM + colg] = hv;  // h0 final
            }
            if (t + 1 < T_STEPS) {
                #pragma unroll
                for (int r = 0; r < 4; ++r) xr[r] = xn[r];
            }
            asm volatile("s_waitcnt vmcnt(0)" ::: "memory");
            __syncthreads();
            if (tid == 0)
                __hip_atomic_store(&f0[cb * FSTRIDE], t + 1, __ATOMIC_RELAXED,
                                   __HIP_MEMORY_SCOPE_AGENT);
        }
    } else {
        // ---------------- layer 1 ----------------
        const float bb = b1[colg];
        int vc0 = 0, vc1 = 0;
        for (int t = 0; t < T_STEPS; ++t) {
            if (wave == 0) {
                while (!__all(vc0 >= t + 1)) {
                    if (vc0 < t + 1) {
                        vc0 = __hip_atomic_load(&f0[lane * FSTRIDE], __ATOMIC_RELAXED,
                                                __HIP_MEMORY_SCOPE_AGENT);
                        if (vc0 < t + 1) __builtin_amdgcn_s_sleep(1);
                    }
                }
            }
            __syncthreads();
            const bf16_t* A0 = h0all + (size_t)(t + 1) * BH;
            bf16x8 av0[32];
            #pragma unroll
            for (int kc = 0; kc < 32; ++kc)
                av0[kc] = *(const bf16x8*)(A0 + arow + kc * 32 + quad * 8);
            __builtin_amdgcn_sched_barrier(0);
            floatx4 aA = fzero, aB = fzero;
            #pragma unroll
            for (int kc = 0; kc < 32; ++kc) {
                bf16x8 wv1 = *(const bf16x8*)(smem + kc * 1024 + lane * 16);
                if (kc & 1) aB = mfma16(av0[kc], wv1, aB);
                else        aA = mfma16(av0[kc], wv1, aA);
            }
            if (t > 0) {
                if (wave == 0) {
                    while (!__all(vc1 >= t)) {
                        if (vc1 < t) {
                            vc1 = __hip_atomic_load(&f1[lane * FSTRIDE], __ATOMIC_RELAXED,
                                                    __HIP_MEMORY_SCOPE_AGENT);
                            if (vc1 < t) __builtin_amdgcn_s_sleep(1);
                        }
                    }
                }
                __syncthreads();
            }
            const bf16_t* A1 = h1all + (size_t)t * BH;
            bf16x8 av1[32];
            #pragma unroll
            for (int kc = 0; kc < 32; ++kc)
                av1[kc] = *(const bf16x8*)(A1 + arow + kc * 32 + quad * 8);
            __builtin_amdgcn_sched_barrier(0);
            #pragma unroll
            for (int kc = 0; kc < 32; ++kc) {
                bf16x8 wv2 = *(const bf16x8*)(smem + 32768 + kc * 1024 + lane * 16);
                if (kc & 1) aB = mfma16(av1[kc], wv2, aB);
                else        aA = mfma16(av1[kc], wv2, aA);
            }
            bf16_t* dst = h1all + (size_t)(t + 1) * BH;
            #pragma unroll
            for (int r = 0; r < 4; ++r) {
                float hv = tanhf(aA[r] + aB[r] + bb);
                store_bf16_bypass(dst + (size_t)(orow0 + r) * HDIM + colg, hv);
                if (t == T_STEPS - 1)
                    out[OUT0 + BH + (size_t)(orow0 + r) * HDIM + colg] = hv;  // h1 final
            }
            asm volatile("s_waitcnt vmcnt(0)" ::: "memory");
            __syncthreads();
            if (tid == 0)
                __hip_atomic_store(&f1[cb * FSTRIDE], t + 1, __ATOMIC_RELAXED,
                                   __HIP_MEMORY_SCOPE_AGENT);
        }
    }
}

// ---------------- launcher ----------------

extern "C" void kernel_launch(void* const* d_in, const int* in_sizes, int n_in,
                              void* d_out, int out_size, void* d_ws, size_t ws_size,
                              hipStream_t stream) {
    (void)in_sizes; (void)n_in; (void)out_size; (void)ws_size;
    const float* emb    = (const float*)d_in[0];
    const float* W_in0  = (const float*)d_in[1];
    const float* Wh0    = (const float*)d_in[2];
    const float* b0     = (const float*)d_in[3];
    const float* W_in1  = (const float*)d_in[4];
    const float* Wh1    = (const float*)d_in[5];
    const float* b1     = (const float*)d_in[6];
    const float* Wdec   = (const float*)d_in[7];
    const float* bdec   = (const float*)d_in[8];
    const float* hidden = (const float*)d_in[9];
    const int*   tokens = (const int*)d_in[10];
    float* out = (float*)d_out;

    char* ws = (char*)d_ws;
    auto alloc = [&](size_t bytes) {
        char* p = ws; ws += (bytes + 255) & ~(size_t)255; return p;
    };
    bf16_t* Xemb  = (bf16_t*)alloc((size_t)MROWS * EDIM * 2);
    bf16_t* X0    = (bf16_t*)alloc((size_t)MROWS * HDIM * 2);
    bf16_t* Win0b = (bf16_t*)alloc((size_t)HDIM * EDIM * 2);
    bf16_t* Wh0b  = (bf16_t*)alloc((size_t)HDIM * HDIM * 2);
    bf16_t* Win1b = (bf16_t*)alloc((size_t)HDIM * HDIM * 2);
    bf16_t* Wh1b  = (bf16_t*)alloc((size_t)HDIM * HDIM * 2);
    bf16_t* Wdecb = (bf16_t*)alloc((size_t)VOCAB * HDIM * 2);
    bf16_t* h1all = (bf16_t*)alloc((size_t)(T_STEPS + 1) * BATCH * HDIM * 2);
    bf16_t* h0all = (bf16_t*)alloc((size_t)(T_STEPS + 1) * BATCH * HDIM * 2);
    int*    flags = (int*)alloc((XF_OFF + 512) * 4);

    setup_kernel<<<dim3(22352), 256, 0, stream>>>(
        emb, W_in0, Wh0, W_in1, Wh1, Wdec, hidden, tokens,
        Xemb, Win0b, Wh0b, Win1b, Wh1b, Wdecb, h0all, h1all, flags);

    fused_kernel<<<dim3(RNN_BLOCKS + DEC_BLOCKS), 256, 0, stream>>>(
        X0, Xemb, Win0b, b0, Wh0b, Win1b, Wh1b, b1, Wdecb, bdec,
        out, h0all, h1all, flags);
}

// Round 9
// 1641.446 us; speedup vs baseline: 1.0020x; 1.0020x over previous
//
#include <hip/hip_runtime.h>
#include <hip/hip_bf16.h>
#include <stdint.h>

typedef __bf16 bf16_t;
typedef __bf16 bf16x8 __attribute__((ext_vector_type(8)));
typedef __bf16 bf16x4 __attribute__((ext_vector_type(4)));
typedef float  floatx4 __attribute__((ext_vector_type(4)));

#define T_STEPS 128
#define BATCH   64
#define EDIM    1024
#define HDIM    1024
#define VOCAB   10000
#define MROWS   (T_STEPS * BATCH)   // 8192
#define RNN_BLOCKS 128              // 64 layer-0 + 64 layer-1
#define DEC_BLOCKS 128              // fused X0+decode consumer blocks
#define BH      (BATCH * HDIM)
#define FSTRIDE 16                  // RNN flags padded to one 64B line each
#define XF_OFF  (128 * FSTRIDE)     // X0-unit flags start here in flags buffer
#define OUT0    ((size_t)MROWS * VOCAB)

__device__ __forceinline__ floatx4 mfma16(bf16x8 a, bf16x8 b, floatx4 c) {
    return __builtin_amdgcn_mfma_f32_16x16x32_bf16(a, b, c, 0, 0, 0);
}

// async global->LDS, 16B per lane. LDS dest wave-uniform base + lane*16;
// global src is PER-LANE (m173). Register-free: queues on vmcnt (depth 63).
__device__ __forceinline__ void gl_lds16(const bf16_t* g, bf16_t* l) {
    __builtin_amdgcn_global_load_lds(
        (const __attribute__((address_space(1))) void*)g,
        (__attribute__((address_space(3))) void*)l, 16, 0, 0);
}

// Coherence-point store: bypasses L1/L2 (sc0 sc1), lands at L3 so other XCDs'
// first-touch plain loads see it WITHOUT any buffer_wbl2/buffer_inv.
__device__ __forceinline__ void store_bf16_bypass(bf16_t* p, float v) {
    union { bf16_t b; unsigned short u; } cv;
    cv.b = (bf16_t)v;
    unsigned int d = cv.u;
    asm volatile("global_store_short %0, %1, off sc0 sc1"
                 :: "v"(p), "v"(d) : "memory");
}

// ---------------- single setup kernel: all f2b + gather + init ----------------

__global__ void setup_kernel(const float* __restrict__ emb,
                             const float* __restrict__ W_in0, const float* __restrict__ Wh0,
                             const float* __restrict__ W_in1, const float* __restrict__ Wh1,
                             const float* __restrict__ Wdec,
                             const float* __restrict__ hidden, const int* __restrict__ tok,
                             bf16_t* __restrict__ Xemb,
                             bf16_t* __restrict__ Win0b, bf16_t* __restrict__ Wh0b,
                             bf16_t* __restrict__ Win1b, bf16_t* __restrict__ Wh1b,
                             bf16_t* __restrict__ Wdecb,
                             bf16_t* __restrict__ h0all, bf16_t* __restrict__ h1all,
                             int* __restrict__ flags) {
    const int b = blockIdx.x, tid = threadIdx.x;
    if (b < 4096) {
        const int which = b >> 10;
        const float* s = which == 0 ? W_in0 : which == 1 ? Wh0 : which == 2 ? W_in1 : Wh1;
        bf16_t*      d = which == 0 ? Win0b : which == 1 ? Wh0b : which == 2 ? Win1b : Wh1b;
        int i = ((b & 1023) * 256 + tid) * 4;
        float4 v = *(const float4*)(s + i);
        bf16x4 o; o.x = (bf16_t)v.x; o.y = (bf16_t)v.y; o.z = (bf16_t)v.z; o.w = (bf16_t)v.w;
        *(bf16x4*)(d + i) = o;
    } else if (b < 14096) {
        int i = ((b - 4096) * 256 + tid) * 4;
        float4 v = *(const float4*)(Wdec + i);
        bf16x4 o; o.x = (bf16_t)v.x; o.y = (bf16_t)v.y; o.z = (bf16_t)v.z; o.w = (bf16_t)v.w;
        *(bf16x4*)(Wdecb + i) = o;
    } else if (b < 22288) {
        int row = b - 14096;
        int t = tok[row];
        int e = tid * 4;
        float4 v = *(const float4*)(emb + (size_t)t * EDIM + e);
        bf16x4 o; o.x = (bf16_t)v.x; o.y = (bf16_t)v.y; o.z = (bf16_t)v.z; o.w = (bf16_t)v.w;
        *(bf16x4*)(Xemb + (size_t)row * EDIM + e) = o;
    } else {
        int i = ((b - 22288) * 256 + tid) * 4;   // 0..65532
        float4 v0 = *(const float4*)(hidden + i);
        float4 v1 = *(const float4*)(hidden + BH + i);
        bf16x4 o0, o1;
        o0.x = (bf16_t)v0.x; o0.y = (bf16_t)v0.y; o0.z = (bf16_t)v0.z; o0.w = (bf16_t)v0.w;
        o1.x = (bf16_t)v1.x; o1.y = (bf16_t)v1.y; o1.z = (bf16_t)v1.z; o1.w = (bf16_t)v1.w;
        *(bf16x4*)(h0all + i) = o0;   // h0[-1] -> slot 0
        *(bf16x4*)(h1all + i) = o1;   // h1[-1] -> slot 0
        if (b == 22288)
            for (int j = tid; j < XF_OFF + 512; j += 256) flags[j] = 0;
    }
}

// ---------------- fused X0-GEMM + RNN + streaming decode ----------------
// 256 blocks, all co-resident:
//   0..63   layer-0, 64..127 layer-1, 128..255 helpers (phase A: X0 GEMM with
//   xf flags; phase B: logits, fixed vocab-tile per block, nt stores).
//
// RNN inner loop (NEW this round): per-wave gl_lds fragment ring. Each MFMA
// A-fragment only touches the wave's own 16 rows, so each wave stages its own
// fragments (1KB each: lane*16 layout -> conflict-free ds_read) into a 16-slot
// LDS ring via register-free global_load_lds, with counted s_waitcnt vmcnt(15)
// (in-order retirement, m135). No cross-wave barriers in the ring. This
// replaces the register-dribble loads (VGPR-bound ~8 in flight, ~5us/step of
// serialized fabric latency across rounds 2-5).

__global__ __launch_bounds__(256, 1) void fused_kernel(
    bf16_t* __restrict__ X0,           // [8192][1024] workspace
    const bf16_t* __restrict__ Xemb,
    const bf16_t* __restrict__ Win0b,
    const float*  __restrict__ b0,
    const bf16_t* __restrict__ Wh0b,
    const bf16_t* __restrict__ Win1b,
    const bf16_t* __restrict__ Wh1b,
    const float*  __restrict__ b1,
    const bf16_t* __restrict__ Wdecb,  // [10000][1024]
    const float*  __restrict__ bdec,
    float* __restrict__ out,           // logits [8192][10000] fp32 + final states
    bf16_t* __restrict__ h0all,        // [129][64][1024], slot s = h0[s-1]
    bf16_t* __restrict__ h1all,        // [129][64][1024], slot s = h1[s-1]
    int* __restrict__ flags)           // f0[64*FS], f1[64*FS], xf[512]
{
    __shared__ __align__(16) char smem[131072];
    const int tid  = threadIdx.x;
    const int lane = tid & 63;
    const int wave = tid >> 6;
    const int quad = lane >> 4;
    const int l16  = lane & 15;
    int* f0 = flags;
    int* f1 = flags + 64 * FSTRIDE;
    int* xf = flags + XF_OFF;
    const floatx4 fzero = {0.f, 0.f, 0.f, 0.f};

    if (blockIdx.x >= RNN_BLOCKS) {
        // ================= helper blocks =================
        const int d  = blockIdx.x - RNN_BLOCKS;
        const int wm = wave & 1;
        const int wn = wave >> 1;
        bf16_t* sA = (bf16_t*)smem;            // 8 KB
        bf16_t* sW = (bf16_t*)(smem + 8192);   // 8 KB

        // ---- phase A: X0 GEMM, t-major units (u -> mtile=u/8, nt=u%8) ----
        for (int u = d; u < 512; u += DEC_BLOCKS) {
            const int mTile = (u >> 3) * 128;
            const int nTile = (u & 7) * 128;
            floatx4 acc[4][4];
            #pragma unroll
            for (int i = 0; i < 4; ++i)
                #pragma unroll
                for (int j = 0; j < 4; ++j) acc[i][j] = fzero;
            for (int kk = 0; kk < EDIM; kk += 32) {
                __syncthreads();
                #pragma unroll
                for (int j = 0; j < 2; ++j) {
                    int c   = tid + j * 256;
                    int row = c >> 2;
                    int sub = c & 3;
                    gl_lds16(Xemb  + (size_t)(mTile + row) * EDIM + kk + sub * 8, sA + c * 8);
                    gl_lds16(Win0b + (size_t)(nTile + row) * EDIM + kk + sub * 8, sW + c * 8);
                }
                __syncthreads();
                bf16x8 af[4], wf[4];
                #pragma unroll
                for (int mi = 0; mi < 4; ++mi)
                    af[mi] = *(const bf16x8*)(sA + (wm * 64 + mi * 16 + l16) * 32 + quad * 8);
                #pragma unroll
                for (int ni = 0; ni < 4; ++ni)
                    wf[ni] = *(const bf16x8*)(sW + (wn * 64 + ni * 16 + l16) * 32 + quad * 8);
                #pragma unroll
                for (int mi = 0; mi < 4; ++mi)
                    #pragma unroll
                    for (int ni = 0; ni < 4; ++ni)
                        acc[mi][ni] = mfma16(af[mi], wf[ni], acc[mi][ni]);
            }
            #pragma unroll
            for (int ni = 0; ni < 4; ++ni) {
                int col = nTile + wn * 64 + ni * 16 + l16;
                float bv = b0[col];
                #pragma unroll
                for (int mi = 0; mi < 4; ++mi) {
                    #pragma unroll
                    for (int r = 0; r < 4; ++r) {
                        int row = mTile + wm * 64 + mi * 16 + quad * 4 + r;
                        store_bf16_bypass(X0 + (size_t)row * HDIM + col,
                                          acc[mi][ni][r] + bv);
                    }
                }
            }
            asm volatile("s_waitcnt vmcnt(0)" ::: "memory");
            __syncthreads();
            if (tid == 0)
                __hip_atomic_store(&xf[u], 1, __ATOMIC_RELAXED, __HIP_MEMORY_SCOPE_AGENT);
            __syncthreads();
        }

        // ---- phase B: logits, fixed-vt, nontemporal stores ----
        int vt, tp0, tpN;
        if (d < 79) { vt = d;      tp0 = 0;  tpN = (d < 49) ? 32 : 64; }
        else        { vt = d - 79; tp0 = 32; tpN = 64; }
        const bf16_t* Adec = h1all + BH;       // row r = h1[r/64][r%64]
        const int nTile = vt * 128;
        int vc = 0;
        for (int tp = tp0; tp < tpN; ++tp) {
            const int need = 2 * tp + 2;
            if (wave == 0) {
                while (!__all(vc >= need)) {
                    if (vc < need) {
                        vc = __hip_atomic_load(&f1[lane * FSTRIDE], __ATOMIC_RELAXED,
                                               __HIP_MEMORY_SCOPE_AGENT);
                        if (vc < need) __builtin_amdgcn_s_sleep(32);
                    }
                }
            }
            __syncthreads();
            const int mTile = tp * 128;
            floatx4 acc[4][4];
            #pragma unroll
            for (int i = 0; i < 4; ++i)
                #pragma unroll
                for (int j = 0; j < 4; ++j) acc[i][j] = fzero;
            for (int kk = 0; kk < HDIM; kk += 32) {
                __syncthreads();
                #pragma unroll
                for (int j = 0; j < 2; ++j) {
                    int c   = tid + j * 256;
                    int row = c >> 2;
                    int sub = c & 3;
                    gl_lds16(Adec + (size_t)(mTile + row) * HDIM + kk + sub * 8, sA + c * 8);
                    int wrow = nTile + row;
                    if (wrow >= VOCAB) wrow = VOCAB - 1;
                    gl_lds16(Wdecb + (size_t)wrow * HDIM + kk + sub * 8, sW + c * 8);
                }
                __syncthreads();
                bf16x8 af[4], wf[4];
                #pragma unroll
                for (int mi = 0; mi < 4; ++mi)
                    af[mi] = *(const bf16x8*)(sA + (wm * 64 + mi * 16 + l16) * 32 + quad * 8);
                #pragma unroll
                for (int ni = 0; ni < 4; ++ni)
                    wf[ni] = *(const bf16x8*)(sW + (wn * 64 + ni * 16 + l16) * 32 + quad * 8);
                #pragma unroll
                for (int mi = 0; mi < 4; ++mi)
                    #pragma unroll
                    for (int ni = 0; ni < 4; ++ni)
                        acc[mi][ni] = mfma16(af[mi], wf[ni], acc[mi][ni]);
            }
            #pragma unroll
            for (int ni = 0; ni < 4; ++ni) {
                int col = nTile + wn * 64 + ni * 16 + l16;
                if (col < VOCAB) {
                    float bv = bdec[col];
                    #pragma unroll
                    for (int mi = 0; mi < 4; ++mi) {
                        #pragma unroll
                        for (int r = 0; r < 4; ++r) {
                            int row = mTile + wm * 64 + mi * 16 + quad * 4 + r;
                            __builtin_nontemporal_store(acc[mi][ni][r] + bv,
                                                        &out[(size_t)row * VOCAB + col]);
                        }
                    }
                }
            }
            __syncthreads();   // LDS reuse guard
        }
        return;
    }

    // ================= RNN blocks =================
    const bool isL1 = blockIdx.x >= 64;
    const int cb    = blockIdx.x & 63;
    const int cbase = cb * 16;
    const int colg  = cbase + l16;
    const int alane = (wave * 16 + l16) * HDIM + quad * 8;   // per-lane fragment src
    const int orow0 = wave * 16 + quad * 4;

    // ---- stage weight slices into LDS (once) ----
    {
        const bf16_t* W0 = isL1 ? Win1b : Wh0b;
        for (int c = tid; c < 2048; c += 256) {
            int kc2 = c >> 6, ln = c & 63;
            const bf16_t* src = W0 + (size_t)(cbase + (ln & 15)) * HDIM + kc2 * 32 + (ln >> 4) * 8;
            *(int4*)(smem + c * 16) = *(const int4*)src;
        }
        if (isL1) {
            for (int c = tid; c < 2048; c += 256) {
                int kc2 = c >> 6, ln = c & 63;
                const bf16_t* src = Wh1b + (size_t)(cbase + (ln & 15)) * HDIM + kc2 * 32 + (ln >> 4) * 8;
                *(int4*)(smem + 32768 + c * 16) = *(const int4*)src;
            }
        }
    }
    __syncthreads();

    if (!isL1) {
        // ---------------- layer 0 ----------------
        const int nt0 = cb >> 3;                 // this block's X0 n-tile
        if (wave == 0 && lane == 0)              // single-lane xf spin (no storm)
            while (__hip_atomic_load(&xf[nt0], __ATOMIC_RELAXED,
                                     __HIP_MEMORY_SCOPE_AGENT) == 0)
                __builtin_amdgcn_s_sleep(2);
        __syncthreads();
        float xr[4];
        #pragma unroll
        for (int r = 0; r < 4; ++r)
            xr[r] = (float)X0[(size_t)(orow0 + r) * HDIM + colg];
        char* ring = smem + 32768 + wave * 16384;  // 16 x 1KB fragment slots
        int vc = 0;
        for (int t = 0; t < T_STEPS; ++t) {
            if (t > 0) {
                if (wave == 0) {
                    int m = (t + 1) >> 1; if (m > 63) m = 63;
                    const int xfi = m * 8 + nt0;
                    int xv = 0;
                    for (;;) {
                        if (vc < t)
                            vc = __hip_atomic_load(&f0[lane * FSTRIDE], __ATOMIC_RELAXED,
                                                   __HIP_MEMORY_SCOPE_AGENT);
                        if (lane == 0 && xv == 0)
                            xv = __hip_atomic_load(&xf[xfi], __ATOMIC_RELAXED,
                                                   __HIP_MEMORY_SCOPE_AGENT);
                        if (__all(vc >= t) && __all(lane != 0 || xv != 0)) break;
                        __builtin_amdgcn_s_sleep(1);
                    }
                }
                __syncthreads();
            }
            const bf16_t* Ap = h0all + (size_t)t * BH;
            float xn[4];
            if (t + 1 < T_STEPS) {   // X0 prefetch; vmcnt counting is offset-proof
                #pragma unroll
                for (int r = 0; r < 4; ++r)
                    xn[r] = (float)X0[((size_t)(t + 1) * BATCH + orow0 + r) * HDIM + colg];
            }
            #pragma unroll
            for (int i = 0; i < 16; ++i)
                gl_lds16(Ap + alane + i * 32, (bf16_t*)(ring + i * 1024));
            floatx4 a0 = fzero, a1 = fzero;
            #pragma unroll
            for (int kc = 0; kc < 32; ++kc) {
                if (kc < 16)      asm volatile("s_waitcnt vmcnt(15)" ::: "memory");
                else if (kc < 20) asm volatile("s_waitcnt vmcnt(12)" ::: "memory");
                else if (kc < 24) asm volatile("s_waitcnt vmcnt(8)"  ::: "memory");
                else if (kc < 28) asm volatile("s_waitcnt vmcnt(4)"  ::: "memory");
                else              asm volatile("s_waitcnt vmcnt(0)"  ::: "memory");
                bf16x8 av = *(const bf16x8*)(ring + (kc & 15) * 1024 + lane * 16);
                if (kc < 16)
                    gl_lds16(Ap + alane + (kc + 16) * 32, (bf16_t*)(ring + (kc & 15) * 1024));
                bf16x8 wv = *(const bf16x8*)(smem + kc * 1024 + lane * 16);
                if (kc & 1) a1 = mfma16(av, wv, a1);
                else        a0 = mfma16(av, wv, a0);
            }
            bf16_t* dst = h0all + (size_t)(t + 1) * BH;
            #pragma unroll
            for (int r = 0; r < 4; ++r) {
                float hv = tanhf(xr[r] + a0[r] + a1[r]);
                store_bf16_bypass(dst + (size_t)(orow0 + r) * HDIM + colg, hv);
                if (t == T_STEPS - 1)
                    out[OUT0 + (size_t)(orow0 + r) * HDIM + colg] = hv;  // h0 final
            }
            if (t + 1 < T_STEPS) {
                #pragma unroll
                for (int r = 0; r < 4; ++r) xr[r] = xn[r];
            }
            asm volatile("s_waitcnt vmcnt(0)" ::: "memory");
            __syncthreads();           // all waves' sc0sc1 stores acked at L3
            if (tid == 0)
                __hip_atomic_store(&f0[cb * FSTRIDE], t + 1, __ATOMIC_RELAXED,
                                   __HIP_MEMORY_SCOPE_AGENT);
        }
    } else {
        // ---------------- layer 1 ----------------
        const float bb = b1[colg];
        char* ring = smem + 65536 + wave * 16384;  // 16 x 1KB fragment slots
        int vc0 = 0, vc1 = 0;
        for (int t = 0; t < T_STEPS; ++t) {
            // combined rendezvous: h0[t] (f0>=t+1) AND h1[t-1] (f1>=t)
            if (wave == 0) {
                while (!(__all(vc0 >= t + 1) && __all(vc1 >= t))) {
                    if (vc0 < t + 1)
                        vc0 = __hip_atomic_load(&f0[lane * FSTRIDE], __ATOMIC_RELAXED,
                                                __HIP_MEMORY_SCOPE_AGENT);
                    if (vc1 < t)
                        vc1 = __hip_atomic_load(&f1[lane * FSTRIDE], __ATOMIC_RELAXED,
                                                __HIP_MEMORY_SCOPE_AGENT);
                    __builtin_amdgcn_s_sleep(1);
                }
            }
            __syncthreads();
            const bf16_t* A0 = h0all + (size_t)(t + 1) * BH;   // h0[t]
            const bf16_t* A1 = h1all + (size_t)t * BH;         // h1[t-1]
            #pragma unroll
            for (int i = 0; i < 16; ++i)
                gl_lds16(A0 + alane + i * 32, (bf16_t*)(ring + i * 1024));
            floatx4 aA = fzero, aB = fzero;
            #pragma unroll
            for (int f = 0; f < 64; ++f) {
                if (f < 48)       asm volatile("s_waitcnt vmcnt(15)" ::: "memory");
                else if (f < 52)  asm volatile("s_waitcnt vmcnt(12)" ::: "memory");
                else if (f < 56)  asm volatile("s_waitcnt vmcnt(8)"  ::: "memory");
                else if (f < 60)  asm volatile("s_waitcnt vmcnt(4)"  ::: "memory");
                else              asm volatile("s_waitcnt vmcnt(0)"  ::: "memory");
                bf16x8 av = *(const bf16x8*)(ring + (f & 15) * 1024 + lane * 16);
                if (f < 48) {
                    const int nf = f + 16;
                    const bf16_t* src = (nf < 32) ? (A0 + alane + nf * 32)
                                                  : (A1 + alane + (nf - 32) * 32);
                    gl_lds16(src, (bf16_t*)(ring + (f & 15) * 1024));
                }
                const char* wbase = (f < 32) ? (const char*)smem : (const char*)(smem + 32768);
                bf16x8 wv = *(const bf16x8*)(wbase + (f & 31) * 1024 + lane * 16);
                if (f & 1) aB = mfma16(av, wv, aB);
                else       aA = mfma16(av, wv, aA);
            }
            bf16_t* dst = h1all + (size_t)(t + 1) * BH;
            #pragma unroll
            for (int r = 0; r < 4; ++r) {
                float hv = tanhf(aA[r] + aB[r] + bb);
                store_bf16_bypass(dst + (size_t)(orow0 + r) * HDIM + colg, hv);
                if (t == T_STEPS - 1)
                    out[OUT0 + BH + (size_t)(orow0 + r) * HDIM + colg] = hv;  // h1 final
            }
            asm volatile("s_waitcnt vmcnt(0)" ::: "memory");
            __syncthreads();
            if (tid == 0)
                __hip_atomic_store(&f1[cb * FSTRIDE], t + 1, __ATOMIC_RELAXED,
                                   __HIP_MEMORY_SCOPE_AGENT);
        }
    }
}

// ---------------- launcher ----------------

extern "C" void kernel_launch(void* const* d_in, const int* in_sizes, int n_in,
                              void* d_out, int out_size, void* d_ws, size_t ws_size,
                              hipStream_t stream) {
    (void)in_sizes; (void)n_in; (void)out_size; (void)ws_size;
    const float* emb    = (const float*)d_in[0];
    const float* W_in0  = (const float*)d_in[1];
    const float* Wh0    = (const float*)d_in[2];
    const float* b0     = (const float*)d_in[3];
    const float* W_in1  = (const float*)d_in[4];
    const float* Wh1    = (const float*)d_in[5];
    const float* b1     = (const float*)d_in[6];
    const float* Wdec   = (const float*)d_in[7];
    const float* bdec   = (const float*)d_in[8];
    const float* hidden = (const float*)d_in[9];
    const int*   tokens = (const int*)d_in[10];
    float* out = (float*)d_out;

    char* ws = (char*)d_ws;
    auto alloc = [&](size_t bytes) {
        char* p = ws; ws += (bytes + 255) & ~(size_t)255; return p;
    };
    bf16_t* Xemb  = (bf16_t*)alloc((size_t)MROWS * EDIM * 2);
    bf16_t* X0    = (bf16_t*)alloc((size_t)MROWS * HDIM * 2);
    bf16_t* Win0b = (bf16_t*)alloc((size_t)HDIM * EDIM * 2);
    bf16_t* Wh0b  = (bf16_t*)alloc((size_t)HDIM * HDIM * 2);
    bf16_t* Win1b = (bf16_t*)alloc((size_t)HDIM * HDIM * 2);
    bf16_t* Wh1b  = (bf16_t*)alloc((size_t)HDIM * HDIM * 2);
    bf16_t* Wdecb = (bf16_t*)alloc((size_t)VOCAB * HDIM * 2);
    bf16_t* h1all = (bf16_t*)alloc((size_t)(T_STEPS + 1) * BATCH * HDIM * 2);
    bf16_t* h0all = (bf16_t*)alloc((size_t)(T_STEPS + 1) * BATCH * HDIM * 2);
    int*    flags = (int*)alloc((XF_OFF + 512) * 4);

    setup_kernel<<<dim3(22352), 256, 0, stream>>>(
        emb, W_in0, Wh0, W_in1, Wh1, Wdec, hidden, tokens,
        Xemb, Win0b, Wh0b, Win1b, Wh1b, Wdecb, h0all, h1all, flags);

    fused_kernel<<<dim3(RNN_BLOCKS + DEC_BLOCKS), 256, 0, stream>>>(
        X0, Xemb, Win0b, b0, Wh0b, Win1b, Wh1b, b1, Wdecb, bdec,
        out, h0all, h1all, flags);
}